// Round 10
// baseline (179.784 us; speedup 1.0000x reference)
//
#include <hip/hip_runtime.h>
#include <cstddef>
#include <cstdint>

// ---------------------------------------------------------------------------
// B=8, N=1024, C=768, H=12, hd=64.  All matmuls mfma_f32_16x16x32_bf16.
// R17: compaction v2 (R16b failed absmax 7.8e-3 -- few-key-scale error).
// Fixes: (1) V gathered with the SAME idx[] as K (pos[]/scatter deleted) so
// K/V per-key alignment is correct BY CONSTRUCTION; idx uses clamped &1023.
// (2) kc/vtc pads zeroed over full [nk,1024).  (3) attn bias path reverted
// to R15's PROVEN mkl-LDS code verbatim, mkl filled from nk
// (j<nk ? 0 : -1e30) -- no new register-guard code.
// Pipeline: cvt3(+8 scan blocks -> idx/nk) -> qkv (R15) -> gather_kv ->
// attn over nkt=ceil(nk/64) tiles -> proj (R15).
// Fixed harness cost: ~42us x2 workspace re-poison fills in the window.
// ---------------------------------------------------------------------------

typedef __attribute__((ext_vector_type(4))) float f32x4;
typedef __attribute__((ext_vector_type(8))) __bf16 bf16x8;
typedef __attribute__((ext_vector_type(4))) unsigned int uint4v;
typedef __attribute__((ext_vector_type(2))) unsigned int uint2v;

#define QK_PRESCALE 0.18033688011112042f   // 64^-0.5 * log2(e); softmax uses exp2

// round-half-up bf16: max error 0.5 ulp
__device__ __forceinline__ unsigned short f2bf(float f) {
  return (unsigned short)((__float_as_uint(f) + 0x8000u) >> 16);
}
// pack two floats -> bf16x2 in one v_perm_b32
__device__ __forceinline__ unsigned int pack2bf(float flo, float fhi) {
  unsigned ulo = __float_as_uint(flo) + 0x8000u;
  unsigned uhi = __float_as_uint(fhi) + 0x8000u;
  return __builtin_amdgcn_perm(uhi, ulo, 0x07060302);
}

// one wave instruction: 64 lanes x 16 B -> LDS[base + lane*16]
__device__ __forceinline__ void gl_lds16(const unsigned short* g, unsigned short* l) {
  __builtin_amdgcn_global_load_lds(
      (const __attribute__((address_space(1))) unsigned int*)g,
      (__attribute__((address_space(3))) unsigned int*)l, 16, 0, 0);
}

// ---------------------------------------------------------------------------
// fp32 -> bf16 conversion for x / qkv_w / proj_w in ONE launch, plus
// 8 trailing blocks (bid >= 8448): per-batch scan of the mask:
//   idx[b][j] = token of j-th unmasked key (stable order), nk[b] = count.
// ---------------------------------------------------------------------------
__global__ __launch_bounds__(256)
void cvt3_kernel(const float* __restrict__ s0, unsigned short* __restrict__ d0,
                 const float* __restrict__ s1, unsigned short* __restrict__ d1,
                 const float* __restrict__ s2, unsigned short* __restrict__ d2,
                 const int* __restrict__ mask, int* __restrict__ idxA,
                 int* __restrict__ nkA) {
  __shared__ int sc[256];
  int bid = blockIdx.x;
  if (bid >= 8448) {
    const int b = bid - 8448;
    const int t = threadIdx.x;
    int4 mv = ((const int4*)(mask + b * 1024))[t];
    int c = (mv.x == 0) + (mv.y == 0) + (mv.z == 0) + (mv.w == 0);
    sc[t] = c;
    __syncthreads();
    for (int off = 1; off < 256; off <<= 1) {
      int v = (t >= off) ? sc[t - off] : 0;
      __syncthreads();
      sc[t] += v;
      __syncthreads();
    }
    int run = sc[t] - c;            // exclusive prefix
#pragma unroll
    for (int i = 0; i < 4; ++i) {
      int tok = t * 4 + i;
      int m = (i == 0) ? mv.x : (i == 1) ? mv.y : (i == 2) ? mv.z : mv.w;
      if (!m) { idxA[b * 1024 + run] = tok; run++; }
    }
    if (t == 0) nkA[b] = sc[255];
    return;
  }
  const float* s; unsigned short* d; int i; int n4;
  if (bid < 6144)      { s = s0; d = d0; i = bid * 256 + threadIdx.x;            n4 = 1572864; }
  else if (bid < 7872) { s = s1; d = d1; i = (bid - 6144) * 256 + threadIdx.x;   n4 = 442368; }
  else                 { s = s2; d = d2; i = (bid - 7872) * 256 + threadIdx.x;   n4 = 147456; }
  if (i < n4) {
    float4 v = ((const float4*)s)[i];
    uint2v o;
    o.x = pack2bf(v.x, v.y);
    o.y = pack2bf(v.z, v.w);
    ((uint2v*)d)[i] = o;
  }
}

// ---------------------------------------------------------------------------
// QKV GEMM: A = wqkv (2304 feature rows), B = x (8192 token rows), K = 768.
// (R15: 192x128 tile, 4 waves, single-buffer 40KB LDS, 3 blocks/CU, grid 768.)
// ---------------------------------------------------------------------------
__global__ __launch_bounds__(256, 3)
void qkv_gemm(const unsigned short* __restrict__ xb, const unsigned short* __restrict__ wb,
              const float* __restrict__ qb, const float* __restrict__ vb,
              unsigned short* __restrict__ qo, unsigned short* __restrict__ ko,
              unsigned short* __restrict__ vto) {
  __shared__ __align__(16) unsigned short lds[20480];  // 40 KiB
  const int tid = threadIdx.x;
  const int lane = tid & 63, wid = tid >> 6;
  const int widu = __builtin_amdgcn_readfirstlane(wid);
  const int lm = lane & 15, lq = lane >> 4;
  const int xsw = lm & 7;
  const int wr = widu >> 1, wc = widu & 1;      // feat-half (96), tok-half (64)
  const int L = blockIdx.x;
  const int xcd = L & 7, s = L >> 3;            // s: 0..95
  const int ft = s >> 3;                        // feature tile 0..11 (192 feats)
  const int tt = xcd * 8 + (s & 7);             // token tile 0..63 (128 toks)
  const int m0 = tt * 128;                      // token base
  const int n0 = ft * 192;                      // feature base
  const int srow = lane >> 3;                   // 0..7
  const int scolsw = ((lane & 7) ^ srow) * 8;   // pre-swizzled source chunk
  const unsigned short* paS = wb + (size_t)(n0 + widu * 48 + srow) * 768 + scolsw;
  const unsigned short* pbS = xb + (size_t)(m0 + widu * 32 + srow) * 768 + scolsw;
  unsigned short* const ldsA = &lds[(widu * 48) * 64];
  unsigned short* const ldsB = &lds[12288 + (widu * 32) * 64];

  f32x4 acc[6][4] = {};

  for (int t = 0; t < 12; ++t) {
    const size_t c = (size_t)t * 64;
#pragma unroll
    for (int i = 0; i < 6; ++i)
      gl_lds16(paS + (size_t)i * 8 * 768 + c, ldsA + i * 8 * 64);
#pragma unroll
    for (int i = 0; i < 4; ++i)
      gl_lds16(pbS + (size_t)i * 8 * 768 + c, ldsB + i * 8 * 64);
    __syncthreads();

    bf16x8 bff[4][2], af[3][2];
#pragma unroll
    for (int n2 = 0; n2 < 4; ++n2)
#pragma unroll
      for (int kx = 0; kx < 2; ++kx)
        bff[n2][kx] = *(const bf16x8*)&lds[12288 + (wc * 64 + n2 * 16 + lm) * 64 + (((kx * 4 + lq) ^ xsw) * 8)];
#pragma unroll
    for (int m2 = 0; m2 < 3; ++m2)
#pragma unroll
      for (int kx = 0; kx < 2; ++kx)
        af[m2][kx] = *(const bf16x8*)&lds[(wr * 96 + m2 * 16 + lm) * 64 + (((kx * 4 + lq) ^ xsw) * 8)];

    __builtin_amdgcn_s_setprio(1);
#pragma unroll
    for (int kx = 0; kx < 2; ++kx)
#pragma unroll
      for (int m2 = 0; m2 < 3; ++m2)
#pragma unroll
        for (int n2 = 0; n2 < 4; ++n2)
          acc[m2][n2] = __builtin_amdgcn_mfma_f32_16x16x32_bf16(af[m2][kx], bff[n2][kx], acc[m2][n2], 0, 0, 0);
    __builtin_amdgcn_s_setprio(0);

    bf16x8 af2[3][2];
#pragma unroll
    for (int m2 = 0; m2 < 3; ++m2)
#pragma unroll
      for (int kx = 0; kx < 2; ++kx)
        af2[m2][kx] = *(const bf16x8*)&lds[(wr * 96 + (3 + m2) * 16 + lm) * 64 + (((kx * 4 + lq) ^ xsw) * 8)];
    __builtin_amdgcn_s_setprio(1);
#pragma unroll
    for (int kx = 0; kx < 2; ++kx)
#pragma unroll
      for (int m2 = 0; m2 < 3; ++m2)
#pragma unroll
        for (int n2 = 0; n2 < 4; ++n2)
          acc[3 + m2][n2] = __builtin_amdgcn_mfma_f32_16x16x32_bf16(af2[m2][kx], bff[n2][kx], acc[3 + m2][n2], 0, 0, 0);
    __builtin_amdgcn_s_setprio(0);

    __syncthreads();
  }

  // ---------------- epilogue ----------------
  const int bq = tt >> 3;
  const int tokb = (tt & 7) * 128;
  if (n0 < 1536) {
    const bool isq = n0 < 768;
    unsigned short* dst0 = isq ? qo : ko;
#pragma unroll
    for (int mi = 0; mi < 6; ++mi) {
      const int fblk = n0 + wr * 96 + mi * 16;
      const int fd = fblk - (isq ? 0 : 768);
      const int hh = fd >> 6;
      const int dih = (fd & 63) + lq * 4;
      f32x4 bias4 = {0.f, 0.f, 0.f, 0.f};
      if (isq) bias4 = *(const f32x4*)&qb[fblk + lq * 4];
#pragma unroll
      for (int ni = 0; ni < 4; ++ni) {
        const int tok = tokb + wc * 64 + ni * 16 + lm;
        uint2v pk;
        if (isq) {
          pk.x = pack2bf((acc[mi][ni][0] + bias4[0]) * QK_PRESCALE,
                         (acc[mi][ni][1] + bias4[1]) * QK_PRESCALE);
          pk.y = pack2bf((acc[mi][ni][2] + bias4[2]) * QK_PRESCALE,
                         (acc[mi][ni][3] + bias4[3]) * QK_PRESCALE);
        } else {
          pk.x = pack2bf(acc[mi][ni][0], acc[mi][ni][1]);
          pk.y = pack2bf(acc[mi][ni][2], acc[mi][ni][3]);
        }
        *(uint2v*)&dst0[(((size_t)(bq * 12 + hh)) * 1024 + tok) * 64 + dih] = pk;
      }
    }
  } else {
    const int vb0 = n0 - 1536;
#pragma unroll
    for (int p = 0; p < 2; ++p) {
      __syncthreads();
      if (wr == p) {
#pragma unroll
        for (int mi = 0; mi < 6; ++mi) {
          f32x4 bias4 = *(const f32x4*)&vb[vb0 + p * 96 + mi * 16 + lq * 4];
#pragma unroll
          for (int ni = 0; ni < 4; ++ni) {
            const int tokl = wc * 64 + ni * 16 + lm;
#pragma unroll
            for (int r = 0; r < 4; ++r)
              lds[(mi * 16 + lq * 4 + r) * 136 + tokl] = f2bf(acc[mi][ni][r] + bias4[r]);
          }
        }
      }
      __syncthreads();
      for (int r = tid >> 1; r < 96; r += 128) {
        const int tq = tid & 1;
        const int dgv = vb0 + p * 96 + r;
        const int hh = dgv >> 6, d = dgv & 63;
        unsigned short* dstv = vto + (((size_t)(bq * 12 + hh)) * 64 + d) * 1024 + tokb + tq * 64;
        const unsigned short* srcr = &lds[r * 136 + tq * 64];
#pragma unroll
        for (int j = 0; j < 8; ++j)
          *(uint4v*)&dstv[j * 8] = *(const uint4v*)&srcr[j * 8];
      }
    }
  }
}

// ---------------------------------------------------------------------------
// gather_kv v2: per bh, compact K rows AND V columns with the SAME idx[]
// (alignment by construction; order-independent).  Pads [nk,1024) zeroed for
// both.  idx uses are clamped &1023 so speculative loads can't fault on
// poisoned entries.  96 blocks x 1024 threads.
// ---------------------------------------------------------------------------
__global__ __launch_bounds__(1024)
void gather_kv(const unsigned short* __restrict__ ko, const unsigned short* __restrict__ vto,
               const int* __restrict__ idxA, const int* __restrict__ nkA,
               unsigned short* __restrict__ kc, unsigned short* __restrict__ vtc) {
  __shared__ int idxL[1024];
  const int bh = blockIdx.x;
  const int b = bh / 12;
  const int t = threadIdx.x;
  const int nk = nkA[b];
  if (t < 256)
    ((int4*)idxL)[t] = ((const int4*)(idxA + b * 1024))[t];
  __syncthreads();
  const int w = t >> 6, lane = t & 63;
  // K: compacted row j <- source row idx[j]; one short per lane (128B rows)
  const unsigned short* kin = ko + (size_t)bh * 65536;
  unsigned short* kout = kc + (size_t)bh * 65536;
  for (int j = w; j < 1024; j += 16) {
    int src = idxL[j] & 1023;
    unsigned short v = kin[(size_t)src * 64 + lane];
    kout[(size_t)j * 64 + lane] = (j < nk) ? v : (unsigned short)0;
  }
  // V: per d-row, compacted col j <- source col idx[j] (same idx as K)
  const unsigned short* vin = vto + (size_t)bh * 65536;
  unsigned short* vout = vtc + (size_t)bh * 65536;
  for (int d = w; d < 64; d += 16) {
    const unsigned short* vr = vin + (size_t)d * 1024;
    unsigned short* vo = vout + (size_t)d * 1024;
    for (int c0 = 0; c0 < 1024; c0 += 64) {
      int j = c0 + lane;
      int src = idxL[j] & 1023;
      unsigned short v = vr[src];
      vo[j] = (j < nk) ? v : (unsigned short)0;
    }
  }
}

// ---------------------------------------------------------------------------
// Flash attention over COMPACTED keys.  768 blocks = 8 XCD x (12 bh x 8 qt).
// nkt = ceil(nk/64) tiles (~8.4 avg vs 16).  Bias path = R15's PROVEN
// mkl-LDS code verbatim; mkl[j] = (j<nk ? 0 : -1e30) built from nk.
// K/V dbuf + async 1-deep prefetch (R12); P->PV in registers via
// v_permlane16_swap_b32 (R14).  LDS 36.9KB -> 4 blocks/CU.
// ---------------------------------------------------------------------------
__global__ __launch_bounds__(256, 4)
void attn_mfma(const unsigned short* __restrict__ q, const unsigned short* __restrict__ kcp,
               const unsigned short* __restrict__ vtc, const int* __restrict__ nkA,
               unsigned short* __restrict__ ao) {
  __shared__ unsigned short ks_s[2][64 * 64];  // dbuf K [key][hd], swizzled chunks
  __shared__ unsigned short vs_s[2][64 * 64];  // dbuf V [hd][key], swizzled chunks
  __shared__ float mkl[1024];                  // compacted-key bias from nk
  const int tid = threadIdx.x;
  const int lane = tid & 63, wid = tid >> 6;
  const int lm = lane & 15, lq = lane >> 4;
  const int xsw = lm & 7;
  const int plq = ((lq & 1) << 1) | (lq >> 1); // V chunk perm {0,2,1,3}
  const int L = blockIdx.x;
  const int xcd = L & 7, s = L >> 3;           // s: 0..95
  const int bh = xcd * 12 + s / 8;
  const int qt = s % 8;
  const int bb = bh / 12, hh = bh % 12;
  const unsigned short* qp = q + (size_t)bh * 65536;
  const unsigned short* kp = kcp + (size_t)bh * 65536;
  const unsigned short* vp = vtc + (size_t)bh * 65536;
  const int nk = nkA[bb];
  int nkt = (nk + 63) >> 6;
  if (nkt < 1) nkt = 1;                        // degenerate-batch guard
  const int q0 = qt * 128 + wid * 32;
  const int srow = lane >> 3;
  const int scolsw = ((lane & 7) ^ srow) * 8;
  const unsigned short* gk = kp + (size_t)(wid * 16 + srow) * 64 + scolsw;
  const unsigned short* gv = vp + (size_t)(wid * 16 + srow) * 1024 + scolsw;

#define STAGE_T(kt_, b_) { \
    gl_lds16(gk + (size_t)(kt_) * 4096, &ks_s[b_][(wid * 16) * 64]); \
    gl_lds16(gk + (size_t)(kt_) * 4096 + (size_t)8 * 64, &ks_s[b_][(wid * 16 + 8) * 64]); \
    gl_lds16(gv + (size_t)(kt_) * 64, &vs_s[b_][(wid * 16) * 64]); \
    gl_lds16(gv + (size_t)(kt_) * 64 + (size_t)8 * 1024, &vs_s[b_][(wid * 16 + 8) * 64]); }

  // mkl[j] = 0 for valid compacted key, -1e30 for pad (same proven path as R15)
  {
    int j4 = tid * 4;
    float4 f;
    f.x = (j4 + 0 < nk) ? 0.0f : -1e30f;
    f.y = (j4 + 1 < nk) ? 0.0f : -1e30f;
    f.z = (j4 + 2 < nk) ? 0.0f : -1e30f;
    f.w = (j4 + 3 < nk) ? 0.0f : -1e30f;
    ((float4*)mkl)[tid] = f;
  }

  bf16x8 qf[2][2];
#pragma unroll
  for (int mi = 0; mi < 2; ++mi)
#pragma unroll
    for (int ks2 = 0; ks2 < 2; ++ks2)
      qf[mi][ks2] = *(const bf16x8*)&qp[(size_t)(q0 + mi * 16 + lm) * 64 + ks2 * 32 + lq * 8];
  bf16x8 ones;
#pragma unroll
  for (int i = 0; i < 8; ++i) ones[i] = (__bf16)1.0f;

  f32x4 o_acc[2][4] = {};
  f32x4 l_acc[2] = {};

  // prologue: stage tile 0; __syncthreads drains vmcnt+lgkm (mkl + stage)
  STAGE_T(0, 0);
  __syncthreads();

  for (int kt = 0; kt < nkt; ++kt) {
    const int b = kt & 1;
    if (kt) {
      asm volatile("s_waitcnt vmcnt(0)\ns_barrier" ::: "memory");
    }
    if (kt + 1 < nkt) STAGE_T(kt + 1, b ^ 1);

    // S^T = K Q^T : col=q=lm, row=key=lq*4+r (+16nt)
    f32x4 st[4][2] = {};
#pragma unroll
    for (int ks2 = 0; ks2 < 2; ++ks2) {
      bf16x8 kf[4];
#pragma unroll
      for (int nt = 0; nt < 4; ++nt)
        kf[nt] = *(const bf16x8*)&ks_s[b][(nt * 16 + lm) * 64 + (((ks2 * 4 + lq) ^ xsw) * 8)];
      __builtin_amdgcn_s_setprio(1);
#pragma unroll
      for (int nt = 0; nt < 4; ++nt)
#pragma unroll
        for (int mi = 0; mi < 2; ++mi)
          st[nt][mi] = __builtin_amdgcn_mfma_f32_16x16x32_bf16(kf[nt], qf[mi][ks2], st[nt][mi], 0, 0, 0);
      __builtin_amdgcn_s_setprio(0);
    }

    // two 32-key halves: softmax (mkl bias) -> permlane transpose -> PV
#pragma unroll
    for (int h2 = 0; h2 < 2; ++h2) {
      bf16x8 pf[2];
#pragma unroll
      for (int mi = 0; mi < 2; ++mi) {
        const int ntA = h2 * 2, ntB = h2 * 2 + 1;
        f32x4 mvA = *(const f32x4*)&mkl[kt * 64 + ntA * 16 + lq * 4];
        f32x4 mvB = *(const f32x4*)&mkl[kt * 64 + ntB * 16 + lq * 4];
        unsigned a0 = pack2bf(__builtin_amdgcn_exp2f(st[ntA][mi][0] + mvA[0]),
                              __builtin_amdgcn_exp2f(st[ntA][mi][1] + mvA[1]));
        unsigned a1 = pack2bf(__builtin_amdgcn_exp2f(st[ntA][mi][2] + mvA[2]),
                              __builtin_amdgcn_exp2f(st[ntA][mi][3] + mvA[3]));
        unsigned b0 = pack2bf(__builtin_amdgcn_exp2f(st[ntB][mi][0] + mvB[0]),
                              __builtin_amdgcn_exp2f(st[ntB][mi][1] + mvB[1]));
        unsigned b1 = pack2bf(__builtin_amdgcn_exp2f(st[ntB][mi][2] + mvB[2]),
                              __builtin_amdgcn_exp2f(st[ntB][mi][3] + mvB[3]));
        // a' = (A0,B0,A2,B2), b' = (A1,B1,A3,B3)
        asm volatile("v_permlane16_swap_b32 %0, %1" : "+v"(a0), "+v"(b0));
        asm volatile("v_permlane16_swap_b32 %0, %1" : "+v"(a1), "+v"(b1));
        uint4v u; u.x = a0; u.y = a1; u.z = b0; u.w = b1;
        pf[mi] = __builtin_bit_cast(bf16x8, u);
      }
      bf16x8 vf[4];
#pragma unroll
      for (int nt = 0; nt < 4; ++nt)
        vf[nt] = *(const bf16x8*)&vs_s[b][(nt * 16 + lm) * 64 + (((h2 * 4 + plq) ^ xsw) * 8)];
      __builtin_amdgcn_s_setprio(1);
#pragma unroll
      for (int mi = 0; mi < 2; ++mi) {
#pragma unroll
        for (int nt = 0; nt < 4; ++nt)
          o_acc[mi][nt] = __builtin_amdgcn_mfma_f32_16x16x32_bf16(pf[mi], vf[nt], o_acc[mi][nt], 0, 0, 0);
        l_acc[mi] = __builtin_amdgcn_mfma_f32_16x16x32_bf16(pf[mi], ones, l_acc[mi], 0, 0, 0);
      }
      __builtin_amdgcn_s_setprio(0);
    }
  }
#undef STAGE_T

  // epilogue: ao[b, tok, h*64+d] = O/l  (bf16)
#pragma unroll
  for (int mi = 0; mi < 2; ++mi) {
#pragma unroll
    for (int r = 0; r < 4; ++r) {
      float inv = 1.0f / l_acc[mi][r];
      int tok = q0 + mi * 16 + lq * 4 + r;
#pragma unroll
      for (int nt = 0; nt < 4; ++nt)
        ao[(size_t)(bb * 1024 + tok) * 768 + hh * 64 + nt * 16 + lm] = f2bf(o_acc[mi][nt][r] * inv);
    }
  }
}

// ---------------------------------------------------------------------------
// Proj GEMM: M=8192, N=768, K=768.  (R15: 96x128 tile, grid 512, 2/CU.)
// ---------------------------------------------------------------------------
__global__ __launch_bounds__(256, 2)
void proj_gemm(const unsigned short* __restrict__ ab, const unsigned short* __restrict__ wb,
               const float* __restrict__ pb, float* __restrict__ out) {
  __shared__ __align__(16) unsigned short lds[14336];  // A 96x64 | B 128x64
  const int tid = threadIdx.x;
  const int lane = tid & 63, wid = tid >> 6;
  const int widu = __builtin_amdgcn_readfirstlane(wid);
  const int lm = lane & 15, lq = lane >> 4;
  const int xsw = lm & 7;
  const int wr = widu >> 1, wc = widu & 1;
  const int L = blockIdx.x;
  const int xcd = L & 7, s = L >> 3;
  const int n0 = (s >> 3) * 96;
  const int m0 = (xcd * 8 + (s & 7)) * 128;
  const int srow = lane >> 3;
  const int scolsw = ((lane & 7) ^ srow) * 8;
  const unsigned short* paS = wb + (size_t)(n0 + widu * 24 + srow) * 768 + scolsw;
  const unsigned short* pbS = ab + (size_t)(m0 + widu * 32 + srow) * 768 + scolsw;
  unsigned short* const ldsA = &lds[(widu * 24) * 64];
  unsigned short* const ldsB = &lds[6144 + (widu * 32) * 64];

  f32x4 acc[3][4] = {};

  for (int t = 0; t < 12; ++t) {
    const size_t c = (size_t)t * 64;
#pragma unroll
    for (int i = 0; i < 3; ++i)
      gl_lds16(paS + (size_t)i * 8 * 768 + c, ldsA + i * 8 * 64);
#pragma unroll
    for (int i = 0; i < 4; ++i)
      gl_lds16(pbS + (size_t)i * 8 * 768 + c, ldsB + i * 8 * 64);
    __syncthreads();

    bf16x8 af[3][2], bff[4][2];
#pragma unroll
    for (int m2 = 0; m2 < 3; ++m2)
#pragma unroll
      for (int kx = 0; kx < 2; ++kx)
        af[m2][kx] = *(const bf16x8*)&lds[(wr * 48 + m2 * 16 + lm) * 64 + (((kx * 4 + lq) ^ xsw) * 8)];
#pragma unroll
    for (int n2 = 0; n2 < 4; ++n2)
#pragma unroll
      for (int kx = 0; kx < 2; ++kx)
        bff[n2][kx] = *(const bf16x8*)&lds[6144 + (wc * 64 + n2 * 16 + lm) * 64 + (((kx * 4 + lq) ^ xsw) * 8)];

    __builtin_amdgcn_s_setprio(1);
#pragma unroll
    for (int kx = 0; kx < 2; ++kx)
#pragma unroll
      for (int m2 = 0; m2 < 3; ++m2)
#pragma unroll
        for (int n2 = 0; n2 < 4; ++n2)
          acc[m2][n2] = __builtin_amdgcn_mfma_f32_16x16x32_bf16(af[m2][kx], bff[n2][kx], acc[m2][n2], 0, 0, 0);
    __builtin_amdgcn_s_setprio(0);

    __syncthreads();
  }

#pragma unroll
  for (int mi = 0; mi < 3; ++mi) {
    int gn0 = n0 + wr * 48 + mi * 16 + lq * 4;
    f32x4 bias4 = *(const f32x4*)&pb[gn0];
#pragma unroll
    for (int ni = 0; ni < 4; ++ni) {
      int gm = m0 + wc * 64 + ni * 16 + lm;
      f32x4 o;
      o[0] = acc[mi][ni][0] + bias4[0];
      o[1] = acc[mi][ni][1] + bias4[1];
      o[2] = acc[mi][ni][2] + bias4[2];
      o[3] = acc[mi][ni][3] + bias4[3];
      *(f32x4*)&out[(size_t)gm * 768 + gn0] = o;
    }
  }
}

// ---------------------------------------------------------------------------
// ws layout (bf16 elts): xb | wqkv | wproj | q | k | v^T | ao | kc | vtc
// then int arrays idx[8192] nk[8]  (~93 MB total; ws ~256 MiB)
// ---------------------------------------------------------------------------
extern "C" void kernel_launch(void* const* d_in, const int* in_sizes, int n_in,
                              void* d_out, int out_size, void* d_ws, size_t ws_size,
                              hipStream_t stream) {
  const float* x      = (const float*)d_in[0];
  const int*   mask   = (const int*)d_in[1];
  const float* qkv_w  = (const float*)d_in[2];
  const float* q_bias = (const float*)d_in[3];
  const float* v_bias = (const float*)d_in[4];
  const float* proj_w = (const float*)d_in[5];
  const float* proj_b = (const float*)d_in[6];
  float* out = (float*)d_out;
  unsigned short* p = (unsigned short*)d_ws;
  unsigned short* xb     = p;              p += 6291456;
  unsigned short* wqkvb  = p;              p += 1769472;
  unsigned short* wprojb = p;              p += 589824;
  unsigned short* qo     = p;              p += 6291456;
  unsigned short* ko     = p;              p += 6291456;
  unsigned short* vto    = p;              p += 6291456;
  unsigned short* ao     = p;              p += 6291456;
  unsigned short* kc     = p;              p += 6291456;
  unsigned short* vtc    = p;              p += 6291456;
  int* idxA = (int*)p;
  int* nkA  = idxA + 8192;

  cvt3_kernel<<<8456, 256, 0, stream>>>(x, xb, qkv_w, wqkvb, proj_w, wprojb,
                                        mask, idxA, nkA);
  qkv_gemm<<<768, 256, 0, stream>>>(xb, wqkvb, q_bias, v_bias, qo, ko, vto);
  gather_kv<<<96, 1024, 0, stream>>>(ko, vto, idxA, nkA, kc, vtc);
  attn_mfma<<<768, 256, 0, stream>>>(qo, kc, vtc, nkA, ao);
  proj_gemm<<<512, 256, 0, stream>>>(ao, wprojb, proj_b, out);
}